// Round 10
// baseline (172.452 us; speedup 1.0000x reference)
//
#include <hip/hip_runtime.h>
#include <hip/hip_bf16.h>
#include <math.h>

#define N 512
#define NN (N*N)
#define D 128
#define DD (D*D)
#define ND (N*D)
#define LSTR 132   // LDS row stride (floats) for 128-wide tiles
#define CSTR 68    // LDS row stride for 64-wide c tile

__device__ __forceinline__ float sigmoidf_(float x) { return 1.f / (1.f + expf(-x)); }

// ---------------- transpose W_mem layers 1..3 for backward ----------------
__global__ void k_transpose(const float* __restrict__ W_mem, float* __restrict__ WT) {
    int idx = blockIdx.x * 256 + threadIdx.x;
    int l = idx / DD;
    int r = idx % DD;
    int i = r / D;
    int j = r % D;
    WT[idx] = W_mem[(l + 1) * DD + j * D + i];
}

// ---------------- phase 1 v3: 4 tokens/block, full-dot threads --------------
// 128 blocks x 512 threads; thread = (tok = tid>>7, j = tid&127).
// Per-thread registers hold h[4], v, pred; ping-pong LDS cur buffers give one
// barrier per round. W traffic per block amortized over 4 tokens.
__global__ __launch_bounds__(512) void k_phase1(
    const float* __restrict__ seq, const float* __restrict__ W_mem,
    const float* __restrict__ W_q, const float* __restrict__ W_kv,
    const float* __restrict__ W_mom, const float* __restrict__ W_step,
    const float* __restrict__ W_decay, const float* __restrict__ WT,
    float* __restrict__ Q, float* __restrict__ INS, float* __restrict__ ES,
    float* __restrict__ am, float* __restrict__ dec)
{
    __shared__ float s_seq[4][D];
    __shared__ float s_bufA[4][D];
    __shared__ float s_bufB[4][D];
    __shared__ float s_red[4][2][3];
    __shared__ float s_lr[4];

    const int tid = threadIdx.x;
    const int tok = tid >> 7;
    const int j   = tid & 127;
    const int t   = blockIdx.x * 4 + tok;

    float sv = seq[t * D + j];
    s_seq[tok][j] = sv;

    // ---- three scalar dots (per token): lr, am, decay ----
    float p0 = sv * W_step[j];
    float p1 = sv * W_mom[j];
    float p2 = sv * W_decay[j];
#pragma unroll
    for (int off = 32; off > 0; off >>= 1) {
        p0 += __shfl_down(p0, off);
        p1 += __shfl_down(p1, off);
        p2 += __shfl_down(p2, off);
    }
    if ((tid & 63) == 0) {
        int w = (tid >> 6) & 1;
        s_red[tok][w][0] = p0;
        s_red[tok][w][1] = p1;
        s_red[tok][w][2] = p2;
    }
    __syncthreads();
    if (j == 0) {
        s_lr[tok] = s_red[tok][0][0] + s_red[tok][1][0];
        am[t]     = s_red[tok][0][1] + s_red[tok][1][1];
        dec[t]    = 1.f - sigmoidf_(s_red[tok][0][2] + s_red[tok][1][2]);
    }

    // ---- k, v, q (full dots; W rows shared by 4 toks via L1) ----
    float kj = 0.f, vj = 0.f, qj = 0.f;
    {
        const float* sq = s_seq[tok];
#pragma unroll 8
        for (int i = 0; i < D; i++) {
            float si = sq[i];
            kj += si * W_kv[i * 256 + j];
            vj += si * W_kv[i * 256 + 128 + j];
            qj += si * W_q[i * 128 + j];
        }
    }
    Q[t * D + j] = qj;
    INS[t * D + j] = kj;
    s_bufA[tok][j] = kj;
    __syncthreads();

    // ---- forward MLP, ping-pong buffers, h in registers ----
    float hreg[4];
    float pred = 0.f;
    {
        float* curs[2] = { &s_bufA[0][0], &s_bufB[0][0] };
        for (int l = 0; l < 4; l++) {
            const float* cur = curs[l & 1] + tok * D;
            float* nxt = curs[(l + 1) & 1] + tok * D;
            const float* Wp = W_mem + l * DD + j;
            float a0 = 0.f, a1 = 0.f, a2 = 0.f, a3 = 0.f;
#pragma unroll 8
            for (int i = 0; i < D; i += 4) {
                a0 += cur[i]     * Wp[i * D];
                a1 += cur[i + 1] * Wp[(i + 1) * D];
                a2 += cur[i + 2] * Wp[(i + 2) * D];
                a3 += cur[i + 3] * Wp[(i + 3) * D];
            }
            float y = (a0 + a1) + (a2 + a3);
            hreg[l] = y;
            if (l < 3) {
                float a = y * sigmoidf_(y);
                nxt[j] = a;
                INS[(l + 1) * ND + t * D + j] = a;
            } else {
                pred = y;
            }
            __syncthreads();
        }

        // ---- e3 = -lr * 2*(pred - v)/D ----
        float e = -s_lr[tok] * (2.f / (float)D) * (pred - vj);
        ES[3 * ND + t * D + j] = e;
        // forward ended with l=3 reading curs[1]; write e into curs[0]
        curs[0][tok * D + j] = e;
        __syncthreads();

        // ---- backward: e_{l-1} = (e_l @ W_l^T) * silu'(h_{l-1}) ----
        for (int l = 3; l >= 1; l--) {
            const float* cur = curs[(3 - l) & 1] + tok * D;
            float* nxt = curs[(3 - l + 1) & 1] + tok * D;
            const float* Wp = WT + (l - 1) * DD + j;
            float a0 = 0.f, a1 = 0.f, a2 = 0.f, a3 = 0.f;
#pragma unroll 8
            for (int i = 0; i < D; i += 4) {
                a0 += cur[i]     * Wp[i * D];
                a1 += cur[i + 1] * Wp[(i + 1) * D];
                a2 += cur[i + 2] * Wp[(i + 2) * D];
                a3 += cur[i + 3] * Wp[(i + 3) * D];
            }
            float g = (a0 + a1) + (a2 + a3);
            float h = hreg[l - 1];
            float sg = sigmoidf_(h);
            float e2 = g * (sg * (1.f + h * (1.f - sg)));
            ES[(l - 1) * ND + t * D + j] = e2;
            nxt[j] = e2;
            __syncthreads();
        }
    }
}

// ---------------- phase 2a: log-space prefix scans ----------------
__global__ __launch_bounds__(512) void k_logscan(
    const float* __restrict__ am, const float* __restrict__ dec,
    double* __restrict__ LA, double* __restrict__ LDp, int* __restrict__ NC)
{
    __shared__ double sa[N], sd[N];
    __shared__ int sn[N];
    const int t = threadIdx.x;
    float a = am[t];
    float d = dec[t];
    sa[t] = log((double)fmaxf(fabsf(a), 1e-38f));
    sd[t] = log((double)fmaxf(d, 1e-38f));
    sn[t] = (a < 0.f) ? 1 : 0;
    __syncthreads();
    for (int off = 1; off < N; off <<= 1) {
        double va = 0.0, vd = 0.0; int vn = 0;
        if (t >= off) { va = sa[t - off]; vd = sd[t - off]; vn = sn[t - off]; }
        __syncthreads();
        sa[t] += va; sd[t] += vd; sn[t] += vn;
        __syncthreads();
    }
    LA[t] = sa[t]; LDp[t] = sd[t]; NC[t] = sn[t];
}

// ---------------- phase 2b: build L_A, L_D ----------------
__global__ __launch_bounds__(256) void k_build(
    const double* __restrict__ LA, const double* __restrict__ LDp,
    const int* __restrict__ NC,
    float* __restrict__ Amat, float* __restrict__ Dmat)
{
    int idx = blockIdx.x * 256 + threadIdx.x;
    int u = idx >> 9;
    int s = idx & (N - 1);
    float va = 0.f, vd = 0.f;
    if (s <= u) {
        va = expf((float)(LA[u] - LA[s]));
        if ((NC[u] - NC[s]) & 1) va = -va;
        vd = expf((float)(LDp[u] - LDp[s]));
    }
    Amat[idx] = va;
    Dmat[idx] = vd;
}

// ---- phase 2c: betaP[z] partial products, split-K<=4 tiles, 2x2 float2 ----
__global__ __launch_bounds__(256) void k_betamm(
    const float* __restrict__ Dmat, const float* __restrict__ Amat,
    float* __restrict__ betaP)
{
    const int bs = blockIdx.x;
    const int bt = blockIdx.y;
    const int z  = blockIdx.z;
    if (bs > bt) return;
    const int span = bt - bs + 1;
    const int chunk = (span + 3) >> 2;
    const int kBeg = bs + z * chunk;
    const int kEnd = (kBeg + chunk < bt + 1) ? (kBeg + chunk) : (bt + 1);
    if (kBeg >= kEnd) return;

    __shared__ float sA[32 * 34];    // [u-k][s-col]
    __shared__ float sDT[32 * 34];   // [u-k][t-row]  (transposed on stage)

    const int tid = threadIdx.x;
    const int tx = tid & 15;
    const int ty = tid >> 4;
    float acc00 = 0.f, acc01 = 0.f, acc10 = 0.f, acc11 = 0.f;

    for (int kt = kBeg; kt < kEnd; kt++) {
        for (int i = tid; i < 1024; i += 256) {
            int r = i >> 5, c = i & 31;
            sA[r * 34 + c]  = Amat[(kt * 32 + r) * N + bs * 32 + c];
            sDT[c * 34 + r] = Dmat[(bt * 32 + r) * N + kt * 32 + c];
        }
        __syncthreads();
#pragma unroll 8
        for (int k = 0; k < 32; k++) {
            float2 a = *(float2*)&sA[k * 34 + 2 * tx];
            float2 d = *(float2*)&sDT[k * 34 + 2 * ty];
            acc00 += d.x * a.x; acc01 += d.x * a.y;
            acc10 += d.y * a.x; acc11 += d.y * a.y;
        }
        __syncthreads();
    }
    float* bp = betaP + z * NN + (bt * 32 + 2 * ty) * N + bs * 32 + 2 * tx;
    *(float2*)bp       = make_float2(acc00, acc01);
    *(float2*)(bp + N) = make_float2(acc10, acc11);
}

// ---- phase 2d: beta = sum of valid slabs; zeros for upper triangle ----
__global__ __launch_bounds__(256) void k_betared(
    const float* __restrict__ betaP, float* __restrict__ beta)
{
    int idx4 = blockIdx.x * 256 + threadIdx.x;
    int t  = idx4 >> 7;
    int s0 = (idx4 & 127) * 4;
    int bt = t >> 5, bs = s0 >> 5;
    float4 v = make_float4(0.f, 0.f, 0.f, 0.f);
    if (bs <= bt) {
        int span = bt - bs + 1;
        int chunk = (span + 3) >> 2;
        int nz = (span + chunk - 1) / chunk;
        v = *(const float4*)(betaP + t * N + s0);
        for (int z = 1; z < nz; z++) {
            float4 u = *(const float4*)(betaP + z * NN + t * N + s0);
            v.x += u.x; v.y += u.y; v.z += u.z; v.w += u.w;
        }
    }
    *(float4*)(beta + t * N + s0) = v;
}

// ---------------- phase 3: one layer, 64-wide s-chunks, v2 register tiling --
__global__ __launch_bounds__(256) void k_layer(
    const float* __restrict__ Xsrc, float* __restrict__ Pout,
    const float* __restrict__ Wl, const float* __restrict__ INSl,
    const float* __restrict__ ESl, const float* __restrict__ beta,
    int mode)
{
    const int r = blockIdx.x;
    const int z = blockIdx.y;
    const bool isW = (z == 8);
    if (!isW && 4 * z > r) return;
    const int t0 = r * 16;
    const int lane = threadIdx.x;

    __shared__ __align__(16) float sX[16 * LSTR];
    __shared__ __align__(16) float sI[64 * LSTR];
    __shared__ __align__(16) float sE[32 * LSTR];
    __shared__ __align__(16) float sc[16 * CSTR];

    const int nzs = (r >> 2) + 1;
#pragma unroll
    for (int i = 0; i < 2; i++) {
        int f4 = lane + 256 * i;
        int row = f4 >> 5, c4 = f4 & 31;
        float4 v = ((const float4*)(Xsrc + t0 * D))[f4];
        if (mode) {
            for (int zz = 1; zz < nzs; zz++) {
                float4 u = ((const float4*)(Xsrc + zz * ND + t0 * D))[f4];
                v.x += u.x; v.y += u.y; v.z += u.z; v.w += u.w;
            }
            float4 w = ((const float4*)(Xsrc + 8 * ND + t0 * D))[f4];
            v.x += w.x; v.y += w.y; v.z += w.z; v.w += w.w;
            v.x = v.x * sigmoidf_(v.x); v.y = v.y * sigmoidf_(v.y);
            v.z = v.z * sigmoidf_(v.z); v.w = v.w * sigmoidf_(v.w);
        }
        *(float4*)(sX + row * LSTR + c4 * 4) = v;
    }

    if (isW) {
        __syncthreads();
        const int ti  = lane >> 4;
        const int j8  = (lane & 15) * 8;
        float acc[8];
#pragma unroll
        for (int b = 0; b < 8; b++) acc[b] = 0.f;
#pragma unroll 4
        for (int k = 0; k < D; k++) {
            float4 w0 = *(const float4*)(Wl + k * D + j8);
            float4 w1 = *(const float4*)(Wl + k * D + j8 + 4);
            float xv = sX[ti * LSTR + k];
            acc[0] += xv * w0.x; acc[1] += xv * w0.y;
            acc[2] += xv * w0.z; acc[3] += xv * w0.w;
            acc[4] += xv * w1.x; acc[5] += xv * w1.y;
            acc[6] += xv * w1.z; acc[7] += xv * w1.w;
        }
        float* yp = Pout + 8 * ND + (t0 + ti) * D + j8;
        *(float4*)yp       = make_float4(acc[0], acc[1], acc[2], acc[3]);
        *(float4*)(yp + 4) = make_float4(acc[4], acc[5], acc[6], acc[7]);
        return;
    }

    const int s0 = z * 64;
#pragma unroll
    for (int i = 0; i < 8; i++) {
        int f4 = lane + 256 * i;
        int row = f4 >> 5, c4 = f4 & 31;
        float4 a = ((const float4*)(INSl + s0 * D))[f4];
        *(float4*)(sI + row * LSTR + c4 * 4) = a;
    }

    const int rp = lane >> 5;
    const int sp = lane & 31;
    float b00 = beta[(t0 + 2 * rp) * N + s0 + sp];
    float b01 = beta[(t0 + 2 * rp) * N + s0 + sp + 32];
    float b10 = beta[(t0 + 2 * rp + 1) * N + s0 + sp];
    float b11 = beta[(t0 + 2 * rp + 1) * N + s0 + sp + 32];
    __syncthreads();

    float g00 = 0.f, g01 = 0.f, g10 = 0.f, g11 = 0.f;
#pragma unroll 8
    for (int k4 = 0; k4 < D; k4 += 4) {
        float4 a0 = *(float4*)(sX + (2 * rp) * LSTR + k4);
        float4 a1 = *(float4*)(sX + (2 * rp + 1) * LSTR + k4);
        float4 p0 = *(float4*)(sI + sp * LSTR + k4);
        float4 p1 = *(float4*)(sI + (sp + 32) * LSTR + k4);
        g00 += a0.x * p0.x + a0.y * p0.y + a0.z * p0.z + a0.w * p0.w;
        g01 += a0.x * p1.x + a0.y * p1.y + a0.z * p1.z + a0.w * p1.w;
        g10 += a1.x * p0.x + a1.y * p0.y + a1.z * p0.z + a1.w * p0.w;
        g11 += a1.x * p1.x + a1.y * p1.y + a1.z * p1.z + a1.w * p1.w;
    }
    sc[(2 * rp) * CSTR + sp]          = g00 * b00;
    sc[(2 * rp) * CSTR + sp + 32]     = g01 * b01;
    sc[(2 * rp + 1) * CSTR + sp]      = g10 * b10;
    sc[(2 * rp + 1) * CSTR + sp + 32] = g11 * b11;

    const int tp = lane >> 5;
    const int jc = (lane & 31) * 4;
    float acc[2][4];
#pragma unroll
    for (int a = 0; a < 2; a++)
#pragma unroll
        for (int b = 0; b < 4; b++) acc[a][b] = 0.f;

    for (int sub = 0; sub < 2; sub++) {
        __syncthreads();
#pragma unroll
        for (int i = 0; i < 4; i++) {
            int f4 = lane + 256 * i;
            int row = f4 >> 5, c4 = f4 & 31;
            float4 b = ((const float4*)(ESl + (s0 + sub * 32) * D))[f4];
            *(float4*)(sE + row * LSTR + c4 * 4) = b;
        }
        __syncthreads();
        const float* scp0 = sc + tp * CSTR + sub * 32;
        const float* scp1 = sc + (tp + 8) * CSTR + sub * 32;
#pragma unroll 8
        for (int s = 0; s < 32; s++) {
            float c0 = scp0[s];
            float c1 = scp1[s];
            float4 e = *(float4*)(sE + s * LSTR + jc);
            acc[0][0] += c0 * e.x; acc[0][1] += c0 * e.y;
            acc[0][2] += c0 * e.z; acc[0][3] += c0 * e.w;
            acc[1][0] += c1 * e.x; acc[1][1] += c1 * e.y;
            acc[1][2] += c1 * e.z; acc[1][3] += c1 * e.w;
        }
    }

    float* yp0 = Pout + z * ND + (t0 + tp) * D + jc;
    float* yp1 = Pout + z * ND + (t0 + tp + 8) * D + jc;
    *(float4*)yp0 = make_float4(acc[0][0], acc[0][1], acc[0][2], acc[0][3]);
    *(float4*)yp1 = make_float4(acc[1][0], acc[1][1], acc[1][2], acc[1][3]);
}

// ---------------- final reduce: out = sum of valid slabs (no silu) ----------
__global__ __launch_bounds__(256) void k_reduce(
    const float* __restrict__ P, float* __restrict__ out)
{
    int f4 = blockIdx.x * 256 + threadIdx.x;
    int t = f4 >> 5;
    int r = t >> 4;
    int nzs = (r >> 2) + 1;
    float4 v = ((const float4*)P)[f4];
    for (int zz = 1; zz < nzs; zz++) {
        float4 u = ((const float4*)(P + zz * ND))[f4];
        v.x += u.x; v.y += u.y; v.z += u.z; v.w += u.w;
    }
    float4 w = ((const float4*)(P + 8 * ND))[f4];
    v.x += w.x; v.y += w.y; v.z += w.z; v.w += w.w;
    ((float4*)out)[f4] = v;
}

extern "C" void kernel_launch(void* const* d_in, const int* in_sizes, int n_in,
                              void* d_out, int out_size, void* d_ws, size_t ws_size,
                              hipStream_t stream) {
    const float* seq     = (const float*)d_in[0];
    const float* W_mem   = (const float*)d_in[1];
    const float* W_q     = (const float*)d_in[2];
    const float* W_kv    = (const float*)d_in[3];
    const float* W_mom   = (const float*)d_in[4];
    const float* W_step  = (const float*)d_in[5];
    const float* W_decay = (const float*)d_in[6];
    float* out = (float*)d_out;

    float* ws   = (float*)d_ws;
    float* am   = ws;                  // N
    float* dec  = am + N;              // N
    float* Q    = dec + N;             // N*D
    float* INS  = Q + ND;              // 4*N*D
    float* ES   = INS + 4 * ND;        // 4*N*D
    float* beta = ES + 4 * ND;         // N*N
    float* WT   = beta + NN;           // 3*D*D
    float* Amat = WT + 3 * DD;         // N*N
    float* Dmat = Amat + NN;           // N*N
    float* Pa   = Dmat + NN;           // 9*N*D
    float* Pb   = Pa + 9 * ND;         // 9*N*D
    double* LA  = (double*)(Pb + 9 * ND);
    double* LDp = LA + N;
    int* NC     = (int*)(LDp + N);
    float* betaP = Pa;                 // 4*N*N aliases Pa+Pb (dead until layer 0)

    k_transpose<<<192, 256, 0, stream>>>(W_mem, WT);
    k_phase1<<<N / 4, 512, 0, stream>>>(seq, W_mem, W_q, W_kv, W_mom, W_step, W_decay,
                                        WT, Q, INS, ES, am, dec);
    k_logscan<<<1, N, 0, stream>>>(am, dec, LA, LDp, NC);
    k_build<<<(NN) / 256, 256, 0, stream>>>(LA, LDp, NC, Amat, Dmat);
    dim3 mmgrid(N / 32, N / 32, 4);
    k_betamm<<<mmgrid, 256, 0, stream>>>(Dmat, Amat, betaP);
    k_betared<<<NN / 4 / 256, 256, 0, stream>>>(betaP, beta);

    dim3 lgrid(32, 9);
    k_layer<<<lgrid, 256, 0, stream>>>(Q,  Pa, W_mem,          INS,          ES,          beta, 0);
    k_layer<<<lgrid, 256, 0, stream>>>(Pa, Pb, W_mem + DD,     INS + ND,     ES + ND,     beta, 1);
    k_layer<<<lgrid, 256, 0, stream>>>(Pb, Pa, W_mem + 2 * DD, INS + 2 * ND, ES + 2 * ND, beta, 1);
    k_layer<<<lgrid, 256, 0, stream>>>(Pa, Pb, W_mem + 3 * DD, INS + 3 * ND, ES + 3 * ND, beta, 1);
    k_reduce<<<64, 256, 0, stream>>>(Pb, out);
}

// Round 11
// 163.515 us; speedup vs baseline: 1.0547x; 1.0547x over previous
//
#include <hip/hip_runtime.h>
#include <hip/hip_bf16.h>
#include <math.h>

#define N 512
#define NN (N*N)
#define D 128
#define DD (D*D)
#define ND (N*D)
#define LSTR 132   // LDS row stride (floats) for 128-wide tiles
#define CSTR 68    // LDS row stride for 64-wide c tile

__device__ __forceinline__ float sigmoidf_(float x) { return 1.f / (1.f + expf(-x)); }

// ---------------- transpose W_mem layers 1..3 for backward ----------------
__global__ void k_transpose(const float* __restrict__ W_mem, float* __restrict__ WT) {
    int idx = blockIdx.x * 256 + threadIdx.x;
    int l = idx / DD;
    int r = idx % DD;
    int i = r / D;
    int j = r % D;
    WT[idx] = W_mem[(l + 1) * DD + j * D + i];
}

// ---------------- phase 1 v4: 2 tokens/block, 4-way split-K, weight reuse ---
// 256 blocks x 512 threads. thread = (p = tid>>7 in 0..3, j = tid&127).
// Each weight load W[i*D+j] feeds BOTH tokens' partial dots (register reuse),
// halving chip-wide weight traffic vs 1 token/block. Owner threads (p<2,
// tok=p) reduce 4 partials and keep h[4]/v/pred in registers.
__global__ __launch_bounds__(512) void k_phase1(
    const float* __restrict__ seq, const float* __restrict__ W_mem,
    const float* __restrict__ W_q, const float* __restrict__ W_kv,
    const float* __restrict__ W_mom, const float* __restrict__ W_step,
    const float* __restrict__ W_decay, const float* __restrict__ WT,
    float* __restrict__ Q, float* __restrict__ INS, float* __restrict__ ES,
    float* __restrict__ am, float* __restrict__ dec)
{
    __shared__ float s_seq[2][D];
    __shared__ float s_bufA[2][D];
    __shared__ float s_bufB[2][D];
    __shared__ float s_p3[4][2][3][D];   // kvq partials [p][tok][d][j]
    __shared__ float s_part[4][2][D];    // GEMV partials [p][tok][j]
    __shared__ float s_red8[8][3];       // per-wave scalar-dot partials
    __shared__ float s_lr[2];

    const int tid = threadIdx.x;
    const int p   = tid >> 7;          // 0..3 split-K part
    const int j   = tid & 127;
    const int t0  = blockIdx.x * 2;
    const int i0  = p * 32;

    // ---- stage both tokens' seq rows ----
    if (p < 2) s_seq[p][j] = seq[(t0 + p) * D + j];
    __syncthreads();

    // ---- scalar dots: waves {4tok,4tok+1} -> step,mom ; {4tok+2,4tok+3} -> decay
    {
        const int wv   = tid >> 6;        // 0..7
        const int tok  = wv >> 2;
        const int half = (wv >> 1) & 1;
        float sv = s_seq[tok][j];
        float p0 = 0.f, p1 = 0.f, p2 = 0.f;
        if (half == 0) { p0 = sv * W_step[j]; p1 = sv * W_mom[j]; }
        else           { p2 = sv * W_decay[j]; }
#pragma unroll
        for (int off = 32; off > 0; off >>= 1) {
            p0 += __shfl_down(p0, off);
            p1 += __shfl_down(p1, off);
            p2 += __shfl_down(p2, off);
        }
        if ((tid & 63) == 0) {
            s_red8[wv][0] = p0; s_red8[wv][1] = p1; s_red8[wv][2] = p2;
        }
    }
    __syncthreads();
    if (tid < 2) {
        int b = tid * 4;
        s_lr[tid]  = s_red8[b][0] + s_red8[b + 1][0];
        am[t0+tid] = s_red8[b][1] + s_red8[b + 1][1];
        dec[t0+tid]= 1.f - sigmoidf_(s_red8[b + 2][2] + s_red8[b + 3][2]);
    }

    // ---- k, v, q: one weight load -> two tokens ----
    float k0 = 0.f, v0 = 0.f, q0 = 0.f;
    float k1 = 0.f, v1 = 0.f, q1 = 0.f;
#pragma unroll 8
    for (int ii = 0; ii < 32; ii++) {
        int i = i0 + ii;
        float wk = W_kv[i * 256 + j];
        float wq = W_q[i * 128 + j];
        float wvv = W_kv[i * 256 + 128 + j];
        float a0 = s_seq[0][i], a1 = s_seq[1][i];
        k0 += a0 * wk;  k1 += a1 * wk;
        v0 += a0 * wvv; v1 += a1 * wvv;
        q0 += a0 * wq;  q1 += a1 * wq;
    }
    s_p3[p][0][0][j] = k0; s_p3[p][0][1][j] = v0; s_p3[p][0][2][j] = q0;
    s_p3[p][1][0][j] = k1; s_p3[p][1][1][j] = v1; s_p3[p][1][2][j] = q1;
    __syncthreads();

    // owners (tok = p < 2) reduce
    float vj = 0.f;
    if (p < 2) {
        const int tok = p;
        float kj = s_p3[0][tok][0][j] + s_p3[1][tok][0][j] + s_p3[2][tok][0][j] + s_p3[3][tok][0][j];
        vj       = s_p3[0][tok][1][j] + s_p3[1][tok][1][j] + s_p3[2][tok][1][j] + s_p3[3][tok][1][j];
        float qj = s_p3[0][tok][2][j] + s_p3[1][tok][2][j] + s_p3[2][tok][2][j] + s_p3[3][tok][2][j];
        Q[(t0 + tok) * D + j] = qj;
        INS[(t0 + tok) * D + j] = kj;
        s_bufA[tok][j] = kj;
    }
    __syncthreads();

    // ---- forward MLP: 4 rounds ----
    float hreg[4];
    float pred = 0.f;
    {
        float (*bufs[2])[D] = { s_bufA, s_bufB };
        for (int l = 0; l < 4; l++) {
            float (*cur)[D] = bufs[l & 1];
            float (*nxt)[D] = bufs[(l + 1) & 1];
            const float* Wp = W_mem + l * DD + j;
            float a0 = 0.f, a1 = 0.f;
#pragma unroll 8
            for (int ii = 0; ii < 32; ii++) {
                int i = i0 + ii;
                float w = Wp[i * D];
                a0 += cur[0][i] * w;
                a1 += cur[1][i] * w;
            }
            s_part[p][0][j] = a0;
            s_part[p][1][j] = a1;
            __syncthreads();
            if (p < 2) {
                const int tok = p;
                float y = (s_part[0][tok][j] + s_part[1][tok][j])
                        + (s_part[2][tok][j] + s_part[3][tok][j]);
                hreg[l] = y;
                if (l < 3) {
                    float a = y * sigmoidf_(y);
                    nxt[tok][j] = a;
                    INS[(l + 1) * ND + (t0 + tok) * D + j] = a;
                } else {
                    pred = y;
                }
            }
            __syncthreads();
        }

        // ---- e3 ----
        if (p < 2) {
            const int tok = p;
            float e = -s_lr[tok] * (2.f / (float)D) * (pred - vj);
            ES[3 * ND + (t0 + tok) * D + j] = e;
            bufs[0][tok][j] = e;   // forward ended reading bufs[1]; write bufs[0]
        }
        __syncthreads();

        // ---- backward: 3 rounds ----
        for (int l = 3; l >= 1; l--) {
            float (*cur)[D] = bufs[(3 - l) & 1];
            float (*nxt)[D] = bufs[(3 - l + 1) & 1];
            const float* Wp = WT + (l - 1) * DD + j;
            float a0 = 0.f, a1 = 0.f;
#pragma unroll 8
            for (int ii = 0; ii < 32; ii++) {
                int i = i0 + ii;
                float w = Wp[i * D];
                a0 += cur[0][i] * w;
                a1 += cur[1][i] * w;
            }
            s_part[p][0][j] = a0;
            s_part[p][1][j] = a1;
            __syncthreads();
            if (p < 2) {
                const int tok = p;
                float g = (s_part[0][tok][j] + s_part[1][tok][j])
                        + (s_part[2][tok][j] + s_part[3][tok][j]);
                float h = hreg[l - 1];
                float sg = sigmoidf_(h);
                float e2 = g * (sg * (1.f + h * (1.f - sg)));
                ES[(l - 1) * ND + (t0 + tok) * D + j] = e2;
                nxt[tok][j] = e2;
            }
            __syncthreads();
        }
    }
}

// ---------------- phase 2a: log-space prefix scans ----------------
__global__ __launch_bounds__(512) void k_logscan(
    const float* __restrict__ am, const float* __restrict__ dec,
    double* __restrict__ LA, double* __restrict__ LDp, int* __restrict__ NC)
{
    __shared__ double sa[N], sd[N];
    __shared__ int sn[N];
    const int t = threadIdx.x;
    float a = am[t];
    float d = dec[t];
    sa[t] = log((double)fmaxf(fabsf(a), 1e-38f));
    sd[t] = log((double)fmaxf(d, 1e-38f));
    sn[t] = (a < 0.f) ? 1 : 0;
    __syncthreads();
    for (int off = 1; off < N; off <<= 1) {
        double va = 0.0, vd = 0.0; int vn = 0;
        if (t >= off) { va = sa[t - off]; vd = sd[t - off]; vn = sn[t - off]; }
        __syncthreads();
        sa[t] += va; sd[t] += vd; sn[t] += vn;
        __syncthreads();
    }
    LA[t] = sa[t]; LDp[t] = sd[t]; NC[t] = sn[t];
}

// ---------------- phase 2b: build L_A, L_D ----------------
__global__ __launch_bounds__(256) void k_build(
    const double* __restrict__ LA, const double* __restrict__ LDp,
    const int* __restrict__ NC,
    float* __restrict__ Amat, float* __restrict__ Dmat)
{
    int idx = blockIdx.x * 256 + threadIdx.x;
    int u = idx >> 9;
    int s = idx & (N - 1);
    float va = 0.f, vd = 0.f;
    if (s <= u) {
        va = expf((float)(LA[u] - LA[s]));
        if ((NC[u] - NC[s]) & 1) va = -va;
        vd = expf((float)(LDp[u] - LDp[s]));
    }
    Amat[idx] = va;
    Dmat[idx] = vd;
}

// ---- phase 2c: betaP[z] partial products, split-K<=4 tiles, 2x2 float2 ----
__global__ __launch_bounds__(256) void k_betamm(
    const float* __restrict__ Dmat, const float* __restrict__ Amat,
    float* __restrict__ betaP)
{
    const int bs = blockIdx.x;
    const int bt = blockIdx.y;
    const int z  = blockIdx.z;
    if (bs > bt) return;
    const int span = bt - bs + 1;
    const int chunk = (span + 3) >> 2;
    const int kBeg = bs + z * chunk;
    const int kEnd = (kBeg + chunk < bt + 1) ? (kBeg + chunk) : (bt + 1);
    if (kBeg >= kEnd) return;

    __shared__ float sA[32 * 34];    // [u-k][s-col]
    __shared__ float sDT[32 * 34];   // [u-k][t-row]  (transposed on stage)

    const int tid = threadIdx.x;
    const int tx = tid & 15;
    const int ty = tid >> 4;
    float acc00 = 0.f, acc01 = 0.f, acc10 = 0.f, acc11 = 0.f;

    for (int kt = kBeg; kt < kEnd; kt++) {
        for (int i = tid; i < 1024; i += 256) {
            int r = i >> 5, c = i & 31;
            sA[r * 34 + c]  = Amat[(kt * 32 + r) * N + bs * 32 + c];
            sDT[c * 34 + r] = Dmat[(bt * 32 + r) * N + kt * 32 + c];
        }
        __syncthreads();
#pragma unroll 8
        for (int k = 0; k < 32; k++) {
            float2 a = *(float2*)&sA[k * 34 + 2 * tx];
            float2 d = *(float2*)&sDT[k * 34 + 2 * ty];
            acc00 += d.x * a.x; acc01 += d.x * a.y;
            acc10 += d.y * a.x; acc11 += d.y * a.y;
        }
        __syncthreads();
    }
    float* bp = betaP + z * NN + (bt * 32 + 2 * ty) * N + bs * 32 + 2 * tx;
    *(float2*)bp       = make_float2(acc00, acc01);
    *(float2*)(bp + N) = make_float2(acc10, acc11);
}

// ---- phase 2d: beta = sum of valid slabs; zeros for upper triangle ----
__global__ __launch_bounds__(256) void k_betared(
    const float* __restrict__ betaP, float* __restrict__ beta)
{
    int idx4 = blockIdx.x * 256 + threadIdx.x;
    int t  = idx4 >> 7;
    int s0 = (idx4 & 127) * 4;
    int bt = t >> 5, bs = s0 >> 5;
    float4 v = make_float4(0.f, 0.f, 0.f, 0.f);
    if (bs <= bt) {
        int span = bt - bs + 1;
        int chunk = (span + 3) >> 2;
        int nz = (span + chunk - 1) / chunk;
        v = *(const float4*)(betaP + t * N + s0);
        for (int z = 1; z < nz; z++) {
            float4 u = *(const float4*)(betaP + z * NN + t * N + s0);
            v.x += u.x; v.y += u.y; v.z += u.z; v.w += u.w;
        }
    }
    *(float4*)(beta + t * N + s0) = v;
}

// ---------------- phase 3: one layer, 64-wide s-chunks, v2 register tiling --
__global__ __launch_bounds__(256) void k_layer(
    const float* __restrict__ Xsrc, float* __restrict__ Pout,
    const float* __restrict__ Wl, const float* __restrict__ INSl,
    const float* __restrict__ ESl, const float* __restrict__ beta,
    int mode)
{
    const int r = blockIdx.x;
    const int z = blockIdx.y;
    const bool isW = (z == 8);
    if (!isW && 4 * z > r) return;
    const int t0 = r * 16;
    const int lane = threadIdx.x;

    __shared__ __align__(16) float sX[16 * LSTR];
    __shared__ __align__(16) float sI[64 * LSTR];
    __shared__ __align__(16) float sE[32 * LSTR];
    __shared__ __align__(16) float sc[16 * CSTR];

    const int nzs = (r >> 2) + 1;
#pragma unroll
    for (int i = 0; i < 2; i++) {
        int f4 = lane + 256 * i;
        int row = f4 >> 5, c4 = f4 & 31;
        float4 v = ((const float4*)(Xsrc + t0 * D))[f4];
        if (mode) {
            for (int zz = 1; zz < nzs; zz++) {
                float4 u = ((const float4*)(Xsrc + zz * ND + t0 * D))[f4];
                v.x += u.x; v.y += u.y; v.z += u.z; v.w += u.w;
            }
            float4 w = ((const float4*)(Xsrc + 8 * ND + t0 * D))[f4];
            v.x += w.x; v.y += w.y; v.z += w.z; v.w += w.w;
            v.x = v.x * sigmoidf_(v.x); v.y = v.y * sigmoidf_(v.y);
            v.z = v.z * sigmoidf_(v.z); v.w = v.w * sigmoidf_(v.w);
        }
        *(float4*)(sX + row * LSTR + c4 * 4) = v;
    }

    if (isW) {
        __syncthreads();
        const int ti  = lane >> 4;
        const int j8  = (lane & 15) * 8;
        float acc[8];
#pragma unroll
        for (int b = 0; b < 8; b++) acc[b] = 0.f;
#pragma unroll 4
        for (int k = 0; k < D; k++) {
            float4 w0 = *(const float4*)(Wl + k * D + j8);
            float4 w1 = *(const float4*)(Wl + k * D + j8 + 4);
            float xv = sX[ti * LSTR + k];
            acc[0] += xv * w0.x; acc[1] += xv * w0.y;
            acc[2] += xv * w0.z; acc[3] += xv * w0.w;
            acc[4] += xv * w1.x; acc[5] += xv * w1.y;
            acc[6] += xv * w1.z; acc[7] += xv * w1.w;
        }
        float* yp = Pout + 8 * ND + (t0 + ti) * D + j8;
        *(float4*)yp       = make_float4(acc[0], acc[1], acc[2], acc[3]);
        *(float4*)(yp + 4) = make_float4(acc[4], acc[5], acc[6], acc[7]);
        return;
    }

    const int s0 = z * 64;
#pragma unroll
    for (int i = 0; i < 8; i++) {
        int f4 = lane + 256 * i;
        int row = f4 >> 5, c4 = f4 & 31;
        float4 a = ((const float4*)(INSl + s0 * D))[f4];
        *(float4*)(sI + row * LSTR + c4 * 4) = a;
    }

    const int rp = lane >> 5;
    const int sp = lane & 31;
    float b00 = beta[(t0 + 2 * rp) * N + s0 + sp];
    float b01 = beta[(t0 + 2 * rp) * N + s0 + sp + 32];
    float b10 = beta[(t0 + 2 * rp + 1) * N + s0 + sp];
    float b11 = beta[(t0 + 2 * rp + 1) * N + s0 + sp + 32];
    __syncthreads();

    float g00 = 0.f, g01 = 0.f, g10 = 0.f, g11 = 0.f;
#pragma unroll 8
    for (int k4 = 0; k4 < D; k4 += 4) {
        float4 a0 = *(float4*)(sX + (2 * rp) * LSTR + k4);
        float4 a1 = *(float4*)(sX + (2 * rp + 1) * LSTR + k4);
        float4 p0 = *(float4*)(sI + sp * LSTR + k4);
        float4 p1 = *(float4*)(sI + (sp + 32) * LSTR + k4);
        g00 += a0.x * p0.x + a0.y * p0.y + a0.z * p0.z + a0.w * p0.w;
        g01 += a0.x * p1.x + a0.y * p1.y + a0.z * p1.z + a0.w * p1.w;
        g10 += a1.x * p0.x + a1.y * p0.y + a1.z * p0.z + a1.w * p0.w;
        g11 += a1.x * p1.x + a1.y * p1.y + a1.z * p1.z + a1.w * p1.w;
    }
    sc[(2 * rp) * CSTR + sp]          = g00 * b00;
    sc[(2 * rp) * CSTR + sp + 32]     = g01 * b01;
    sc[(2 * rp + 1) * CSTR + sp]      = g10 * b10;
    sc[(2 * rp + 1) * CSTR + sp + 32] = g11 * b11;

    const int tp = lane >> 5;
    const int jc = (lane & 31) * 4;
    float acc[2][4];
#pragma unroll
    for (int a = 0; a < 2; a++)
#pragma unroll
        for (int b = 0; b < 4; b++) acc[a][b] = 0.f;

    for (int sub = 0; sub < 2; sub++) {
        __syncthreads();
#pragma unroll
        for (int i = 0; i < 4; i++) {
            int f4 = lane + 256 * i;
            int row = f4 >> 5, c4 = f4 & 31;
            float4 b = ((const float4*)(ESl + (s0 + sub * 32) * D))[f4];
            *(float4*)(sE + row * LSTR + c4 * 4) = b;
        }
        __syncthreads();
        const float* scp0 = sc + tp * CSTR + sub * 32;
        const float* scp1 = sc + (tp + 8) * CSTR + sub * 32;
#pragma unroll 8
        for (int s = 0; s < 32; s++) {
            float c0 = scp0[s];
            float c1 = scp1[s];
            float4 e = *(float4*)(sE + s * LSTR + jc);
            acc[0][0] += c0 * e.x; acc[0][1] += c0 * e.y;
            acc[0][2] += c0 * e.z; acc[0][3] += c0 * e.w;
            acc[1][0] += c1 * e.x; acc[1][1] += c1 * e.y;
            acc[1][2] += c1 * e.z; acc[1][3] += c1 * e.w;
        }
    }

    float* yp0 = Pout + z * ND + (t0 + tp) * D + jc;
    float* yp1 = Pout + z * ND + (t0 + tp + 8) * D + jc;
    *(float4*)yp0 = make_float4(acc[0][0], acc[0][1], acc[0][2], acc[0][3]);
    *(float4*)yp1 = make_float4(acc[1][0], acc[1][1], acc[1][2], acc[1][3]);
}

// ---------------- final reduce: out = sum of valid slabs (no silu) ----------
__global__ __launch_bounds__(256) void k_reduce(
    const float* __restrict__ P, float* __restrict__ out)
{
    int f4 = blockIdx.x * 256 + threadIdx.x;
    int t = f4 >> 5;
    int r = t >> 4;
    int nzs = (r >> 2) + 1;
    float4 v = ((const float4*)P)[f4];
    for (int zz = 1; zz < nzs; zz++) {
        float4 u = ((const float4*)(P + zz * ND))[f4];
        v.x += u.x; v.y += u.y; v.z += u.z; v.w += u.w;
    }
    float4 w = ((const float4*)(P + 8 * ND))[f4];
    v.x += w.x; v.y += w.y; v.z += w.z; v.w += w.w;
    ((float4*)out)[f4] = v;
}

extern "C" void kernel_launch(void* const* d_in, const int* in_sizes, int n_in,
                              void* d_out, int out_size, void* d_ws, size_t ws_size,
                              hipStream_t stream) {
    const float* seq     = (const float*)d_in[0];
    const float* W_mem   = (const float*)d_in[1];
    const float* W_q     = (const float*)d_in[2];
    const float* W_kv    = (const float*)d_in[3];
    const float* W_mom   = (const float*)d_in[4];
    const float* W_step  = (const float*)d_in[5];
    const float* W_decay = (const float*)d_in[6];
    float* out = (float*)d_out;

    float* ws   = (float*)d_ws;
    float* am   = ws;                  // N
    float* dec  = am + N;              // N
    float* Q    = dec + N;             // N*D
    float* INS  = Q + ND;              // 4*N*D
    float* ES   = INS + 4 * ND;        // 4*N*D
    float* beta = ES + 4 * ND;         // N*N
    float* WT   = beta + NN;           // 3*D*D
    float* Amat = WT + 3 * DD;         // N*N
    float* Dmat = Amat + NN;           // N*N
    float* Pa   = Dmat + NN;           // 9*N*D
    float* Pb   = Pa + 9 * ND;         // 9*N*D
    double* LA  = (double*)(Pb + 9 * ND);
    double* LDp = LA + N;
    int* NC     = (int*)(LDp + N);
    float* betaP = Pa;                 // 4*N*N aliases Pa+Pb (dead until layer 0)

    k_transpose<<<192, 256, 0, stream>>>(W_mem, WT);
    k_phase1<<<N / 2, 512, 0, stream>>>(seq, W_mem, W_q, W_kv, W_mom, W_step, W_decay,
                                        WT, Q, INS, ES, am, dec);
    k_logscan<<<1, N, 0, stream>>>(am, dec, LA, LDp, NC);
    k_build<<<(NN) / 256, 256, 0, stream>>>(LA, LDp, NC, Amat, Dmat);
    dim3 mmgrid(N / 32, N / 32, 4);
    k_betamm<<<mmgrid, 256, 0, stream>>>(Dmat, Amat, betaP);
    k_betared<<<NN / 4 / 256, 256, 0, stream>>>(betaP, beta);

    dim3 lgrid(32, 9);
    k_layer<<<lgrid, 256, 0, stream>>>(Q,  Pa, W_mem,          INS,          ES,          beta, 0);
    k_layer<<<lgrid, 256, 0, stream>>>(Pa, Pb, W_mem + DD,     INS + ND,     ES + ND,     beta, 1);
    k_layer<<<lgrid, 256, 0, stream>>>(Pb, Pa, W_mem + 2 * DD, INS + 2 * ND, ES + 2 * ND, beta, 1);
    k_layer<<<lgrid, 256, 0, stream>>>(Pa, Pb, W_mem + 3 * DD, INS + 3 * ND, ES + 3 * ND, beta, 1);
    k_reduce<<<64, 256, 0, stream>>>(Pb, out);
}